// Round 7
// baseline (496.300 us; speedup 1.0000x reference)
//
#include <hip/hip_runtime.h>

#define B_ 8
#define N_ 512
#define D_ 256
#define H_ 8
#define HD_ 32
#define E_ 8192
#define EA_ 32

// log(1e-6)
#define LOG1EM6 -13.815510557964274f
// 1/sqrt(32)
#define SCALE 0.17677669529663687f

// ---------------------------------------------------------------------------
// Kernel 1: QKV projection GEMM.  x:(B*N,256) @ W:(256,768) + b
// 64x64 tile, 256 threads, 4x4 per thread -> 768 blocks, ~3 blocks/CU.
// Output scattered into qkv[3][B][H][N][HD] so K/V panels are contiguous.
// ---------------------------------------------------------------------------
__global__ __launch_bounds__(256) void qkv_gemm(
    const float* __restrict__ x, const float* __restrict__ W,
    const float* __restrict__ bias, float* __restrict__ qkv)
{
    __shared__ float As[16][64];
    __shared__ float Bs[16][64];
    const int tid = threadIdx.x;
    const int m0 = blockIdx.y * 64;
    const int n0 = blockIdx.x * 64;
    const int tx = tid & 15, ty = tid >> 4;

    float acc[4][4];
#pragma unroll
    for (int i = 0; i < 4; i++)
#pragma unroll
        for (int j = 0; j < 4; j++) acc[i][j] = 0.0f;

    for (int kc = 0; kc < 256; kc += 16) {
        {   // A tile: 64 rows x 16 k  (transpose into As[k][row])
            int r  = tid >> 2;            // 0..63
            int c4 = tid & 3;             // k-quad
            float4 v = *(const float4*)&x[(m0 + r) * 256 + kc + c4 * 4];
            As[c4 * 4 + 0][r] = v.x;
            As[c4 * 4 + 1][r] = v.y;
            As[c4 * 4 + 2][r] = v.z;
            As[c4 * 4 + 3][r] = v.w;
        }
        {   // B tile: 16 k x 64 cols
            int kr = tid >> 4;            // 0..15
            int c4 = tid & 15;            // 0..15
            *(float4*)&Bs[kr][c4 * 4] =
                *(const float4*)&W[(kc + kr) * 768 + n0 + c4 * 4];
        }
        __syncthreads();
#pragma unroll
        for (int k = 0; k < 16; k++) {
            float a[4], bb[4];
            *(float4*)&a[0]  = *(float4*)&As[k][ty * 4];
            *(float4*)&bb[0] = *(float4*)&Bs[k][tx * 4];
#pragma unroll
            for (int i = 0; i < 4; i++)
#pragma unroll
                for (int j = 0; j < 4; j++) acc[i][j] += a[i] * bb[j];
        }
        __syncthreads();
    }

    const int col0  = n0 + tx * 4;
    const int which = col0 >> 8;
    const int h     = (col0 >> 5) & 7;
    const int hd0   = col0 & 31;
#pragma unroll
    for (int i = 0; i < 4; i++) {
        int row = m0 + ty * 4 + i;
        int b = row >> 9, n = row & 511;
        float* dst = qkv + (((size_t)(which * B_ + b) * H_ + h) * N_ + n) * HD_ + hd0;
#pragma unroll
        for (int j = 0; j < 4; j++) dst[j] = acc[i][j] + bias[col0 + j];
    }
}

// ---------------------------------------------------------------------------
// Kernel 2: per-edge modified focus log + scatter-winner selection.
// ---------------------------------------------------------------------------
__global__ __launch_bounds__(256) void edge_kernel(
    const float* __restrict__ edge_attr, const int* __restrict__ edge_index,
    const float* __restrict__ adj,
    const float* __restrict__ ds_W, const float* __restrict__ ds_b,
    const float* __restrict__ dw_W, const float* __restrict__ dw_b,
    const float* __restrict__ shifts, const float* __restrict__ widths,
    float* __restrict__ mlog, int* __restrict__ sel)
{
    __shared__ float ea[256 * 33];
    __shared__ float dsW[256], dwW[256];
    const int tid = threadIdx.x;
    const int b   = blockIdx.x >> 5;
    const int e0  = (blockIdx.x & 31) * 256;

    const float* eabase = edge_attr + ((size_t)b * E_ + e0) * EA_;
#pragma unroll
    for (int it = 0; it < 32; it++) {
        int i = tid + it * 256;
        ea[(i >> 5) * 33 + (i & 31)] = eabase[i];
    }
    dsW[tid] = ds_W[tid];
    dwW[tid] = dw_W[tid];
    __syncthreads();

    const int e  = e0 + tid;
    const int eu = edge_index[(size_t)b * 2 * E_ + e];
    const int ev = edge_index[(size_t)b * 2 * E_ + E_ + e];
    const float d = adj[((size_t)b * N_ + eu) * N_ + ev];

    float ds[8], dw[8];
#pragma unroll
    for (int h = 0; h < 8; h++) { ds[h] = ds_b[h]; dw[h] = dw_b[h]; }
#pragma unroll
    for (int k = 0; k < 32; k++) {
        float a = ea[tid * 33 + k];
#pragma unroll
        for (int h = 0; h < 8; h++) {
            ds[h] += a * dsW[k * 8 + h];
            dw[h] += a * dwW[k * 8 + h];
        }
    }
#pragma unroll
    for (int h = 0; h < 8; h++) {
        float ms = shifts[h] + ds[h];
        float mw = widths[h] + dw[h];
        float t  = d - ms;
        float ml = fmaxf(-(t * t) / (2.0f * mw * mw + 1e-6f), LOG1EM6);
        mlog[((size_t)(b * H_ + h)) * E_ + e] = ml;
    }
    atomicMax(&sel[((size_t)b * N_ + eu) * N_ + ev], e);
}

// ---------------------------------------------------------------------------
// lane reduction helper: fold 2*CNT partials across lane-pairs at XOR=MASK
// ---------------------------------------------------------------------------
template <int CNT, int MASK>
__device__ __forceinline__ void red_stage(float* part, int lane)
{
    const bool up = (lane & MASK) != 0;
#pragma unroll
    for (int k = 0; k < CNT; k++) {
        float send = up ? part[k] : part[k + CNT];
        float recv = __shfl_xor(send, MASK, 64);
        part[k] = (up ? part[k + CNT] : part[k]) + recv;
    }
}

// ---------------------------------------------------------------------------
// Kernel 3 v7: fused scores + focus/override/self-loop + softmax + PV.
// 256 threads, launch_bounds(256,2): VGPR cap 128 (proven: r5), and the
// structure is re-cut so the live set FITS 128 without spilling:
//  - PV split into two 16-dim half-passes: partials 64 -> 32 live VGPRs.
//    Same V-read count, same FMA count, ~same shuffle count.
//  - adj/sel prefetched BEFORE QK^T (r6 lesson: inline loads on the
//    softmax critical path cost +60%).
//  - V in LDS exactly 64KB, XOR-swizzled float4 index (conflict-free
//    write+read, r6); 2 x 64KB co-resident (proven r5).
//  - K streamed from global/L2 (rows pair-share each 128B K row).
//  - Q via wave-uniform scalar loads (SGPRs).
// Occupancy: VGPR<=128 & LDS 64KB -> 2 blocks/CU = 2 waves/SIMD.
// ---------------------------------------------------------------------------
__global__ __launch_bounds__(256, 2) void attn_kernel(
    const float* __restrict__ qkv, const float* __restrict__ adj,
    const float* __restrict__ mlog, const int* __restrict__ sel,
    const float* __restrict__ shifts, const float* __restrict__ widths,
    const float* __restrict__ slw_arr, float* __restrict__ out)
{
    extern __shared__ float V_lds[];        // [512][32] floats = 64KB, swizzled

    const int tid = threadIdx.x;
    const int bid = blockIdx.x;             // b*64 + h*8 + rt
    const int b  = bid >> 6;
    const int h  = (bid >> 3) & 7;
    const int rt = bid & 7;
    const int u0 = rt * 64;

    const float* Kg = qkv + ((size_t)(1 * B_ + b) * H_ + h) * N_ * HD_;
    const float* Vg = qkv + ((size_t)(2 * B_ + b) * H_ + h) * N_ * HD_;
    const float* Qg = qkv + ((size_t)(0 * B_ + b) * H_ + h) * N_ * HD_;

    // stage V into LDS with XOR-swizzled float4 index (conflict-free)
#pragma unroll
    for (int it = 0; it < 16; it++) {
        int i4 = tid + it * 256;            // 0..4095 float4s
        int v  = i4 >> 3;
        int d4 = i4 & 7;
        *(float4*)&V_lds[v * 32 + ((d4 ^ (v & 7)) * 4)] = ((const float4*)Vg)[i4];
    }
    __syncthreads();

    const float s_h   = shifts[h];
    const float w_h   = widths[h];
    const float inv2w = 1.0f / (2.0f * w_h * w_h + 1e-6f);
    const float slw   = slw_arr[h];

    const int wv   = tid >> 6;              // 0..3
    const int lane = tid & 63;
    const float* mlg = mlog + ((size_t)(b * H_ + h)) * E_;

    for (int g = 0; g < 8; g++) {
        // global row index of row 0 of this group — wave-uniform
        const int ul0 = __builtin_amdgcn_readfirstlane(u0 + wv * 16 + g * 2);
        const float* Q0 = Qg + ul0 * 32;    // uniform -> scalar loads
        const float* Q1 = Q0 + 32;

        // prefetch adj + sel for the 2 rows (in flight under QK^T)
        float adjv[2][8];
        int   selv[2][8];
#pragma unroll
        for (int r = 0; r < 2; r++) {
            const float* arow = adj + ((size_t)b * N_ + ul0 + r) * N_;
            const int*   srow = sel + ((size_t)b * N_ + ul0 + r) * N_;
#pragma unroll
            for (int j = 0; j < 8; j++) {
                adjv[r][j] = arow[lane + 64 * j];
                selv[r][j] = srow[lane + 64 * j];
            }
        }

        // QK^T: j-outer, each lane streams one contiguous 128B K row per j
        float acc[2][8];
#pragma unroll
        for (int j = 0; j < 8; j++) {
            const float* Krow = Kg + (size_t)(lane + 64 * j) * 32;
            float a0 = 0.0f, a1 = 0.0f;
#pragma unroll
            for (int d4 = 0; d4 < 8; d4++) {
                float4 k4 = *(const float4*)&Krow[d4 * 4];
                float4 q0 = *(const float4*)&Q0[d4 * 4];   // SGPR broadcast
                float4 q1 = *(const float4*)&Q1[d4 * 4];
                a0 += q0.x * k4.x + q0.y * k4.y + q0.z * k4.z + q0.w * k4.w;
                a1 += q1.x * k4.x + q1.y * k4.y + q1.z * k4.z + q1.w * k4.w;
            }
            acc[0][j] = a0;
            acc[1][j] = a1;
        }

        // adjust + softmax for both rows (independent chains interleave)
        float p[2][8];
#pragma unroll
        for (int r = 0; r < 2; r++) {
            const int u = ul0 + r;
            float af[8];
#pragma unroll
            for (int j = 0; j < 8; j++) {
                float a  = acc[r][j] * SCALE;
                int   sv = selv[r][j];
                float ov;
                if (sv >= 0) {
                    ov = mlg[sv];           // edge override (replaces baseline)
                } else {
                    float t = adjv[r][j] - s_h;
                    ov = fmaxf(-(t * t) * inv2w, LOG1EM6);
                }
                a += ov;
                if (lane + 64 * j == u) a += slw;   // self-loop
                af[j] = a;
            }
            float m = af[0];
#pragma unroll
            for (int j = 1; j < 8; j++) m = fmaxf(m, af[j]);
#pragma unroll
            for (int mk = 32; mk >= 1; mk >>= 1)
                m = fmaxf(m, __shfl_xor(m, mk, 64));
            float ssum = 0.0f;
#pragma unroll
            for (int j = 0; j < 8; j++) {
                p[r][j] = __expf(af[j] - m);
                ssum += p[r][j];
            }
#pragma unroll
            for (int mk = 32; mk >= 1; mk >>= 1)
                ssum += __shfl_xor(ssum, mk, 64);
            const float pinv = 1.0f / ssum;
#pragma unroll
            for (int j = 0; j < 8; j++) p[r][j] *= pinv;
        }

        // PV in two 16-dim half-passes (keeps partials at 32 live VGPRs)
#pragma unroll
        for (int h4 = 0; h4 < 2; h4++) {
            float pa[16], pb[16];
#pragma unroll
            for (int d = 0; d < 16; d++) { pa[d] = 0.0f; pb[d] = 0.0f; }
#pragma unroll
            for (int dq = 0; dq < 4; dq++) {
                const int d4 = h4 * 4 + dq;
#pragma unroll
                for (int j = 0; j < 8; j++) {
                    int vv = lane + 64 * j;
                    float4 v4 = *(float4*)&V_lds[vv * 32 + ((d4 ^ (vv & 7)) * 4)];
                    pa[dq * 4 + 0] += p[0][j] * v4.x;
                    pa[dq * 4 + 1] += p[0][j] * v4.y;
                    pa[dq * 4 + 2] += p[0][j] * v4.z;
                    pa[dq * 4 + 3] += p[0][j] * v4.w;
                    pb[dq * 4 + 0] += p[1][j] * v4.x;
                    pb[dq * 4 + 1] += p[1][j] * v4.y;
                    pb[dq * 4 + 2] += p[1][j] * v4.z;
                    pb[dq * 4 + 3] += p[1][j] * v4.w;
                }
            }
            // fold 16 dims over lane bits 5..2 (both rows interleave)
            red_stage<8, 32>(pa, lane);  red_stage<8, 32>(pb, lane);
            red_stage<4, 16>(pa, lane);  red_stage<4, 16>(pb, lane);
            red_stage<2, 8>(pa, lane);   red_stage<2, 8>(pb, lane);
            red_stage<1, 4>(pa, lane);   red_stage<1, 4>(pb, lane);
            // fold lane bit 1
            pa[0] += __shfl_xor(pa[0], 2, 64);
            pb[0] += __shfl_xor(pb[0], 2, 64);
            // fold lane bit 0 + row swap: even lane -> row0, odd -> row1
            float send = (lane & 1) ? pa[0] : pb[0];
            float recv = __shfl_xor(send, 1, 64);
            float keep = (lane & 1) ? pb[0] : pa[0];
            float tot  = keep + recv;
            if (!(lane & 2)) {
                int dd   = h4 * 16 + (lane >> 2);
                int urow = ul0 + (lane & 1);
                out[((size_t)b * N_ + urow) * D_ + h * HD_ + dd] = tot;
            }
        }
    }
}

// ---------------------------------------------------------------------------
extern "C" void kernel_launch(void* const* d_in, const int* in_sizes, int n_in,
                              void* d_out, int out_size, void* d_ws, size_t ws_size,
                              hipStream_t stream)
{
    const float* x          = (const float*)d_in[0];
    const float* adj        = (const float*)d_in[1];
    const int*   edge_index = (const int*)d_in[2];
    const float* edge_attr  = (const float*)d_in[3];
    const float* qkv_W      = (const float*)d_in[6];
    const float* qkv_b      = (const float*)d_in[7];
    const float* ds_W       = (const float*)d_in[12];
    const float* ds_b       = (const float*)d_in[13];
    const float* dw_W       = (const float*)d_in[14];
    const float* dw_b       = (const float*)d_in[15];
    const float* shifts     = (const float*)d_in[16];
    const float* widths     = (const float*)d_in[17];
    const float* slw        = (const float*)d_in[18];
    float* out = (float*)d_out;

    float* qkv  = (float*)d_ws;                              // 3*B*H*N*HD f32
    float* mlog = qkv + (size_t)3 * B_ * H_ * N_ * HD_;      // B*H*E f32
    int*   sel  = (int*)(mlog + (size_t)B_ * H_ * E_);       // B*N*N i32

    hipMemsetAsync(sel, 0xFF, (size_t)B_ * N_ * N_ * sizeof(int), stream);

    qkv_gemm<<<dim3(12, 64), 256, 0, stream>>>(x, qkv_W, qkv_b, qkv);

    edge_kernel<<<dim3(256), 256, 0, stream>>>(edge_attr, edge_index, adj,
                                               ds_W, ds_b, dw_W, dw_b,
                                               shifts, widths, mlog, sel);

    hipFuncSetAttribute((const void*)attn_kernel,
                        hipFuncAttributeMaxDynamicSharedMemorySize, 65536);
    attn_kernel<<<dim3(512), 256, 65536, stream>>>(qkv, adj, mlog, sel,
                                                   shifts, widths, slw, out);
}

// Round 10
// 86.278 us; speedup vs baseline: 5.7523x; 5.7523x over previous
//
#include <hip/hip_runtime.h>

#define B_ 8
#define N_ 512
#define D_ 256
#define H_ 8
#define HD_ 32
#define E_ 8192
#define EA_ 32

#define LOG1EM6 -13.815510557964274f
#define SCALE 0.17677669529663687f

typedef _Float16 half8 __attribute__((ext_vector_type(8)));
typedef _Float16 half4t __attribute__((ext_vector_type(4)));
typedef __fp16 fp16x2 __attribute__((ext_vector_type(2)));
typedef float f32x16 __attribute__((ext_vector_type(16)));

// ---------------------------------------------------------------------------
// Kernel 1: QKV projection GEMM (f32 core, proven). Epilogue emits f16:
//   Qh[b][h][n][32] (pre-scaled by 1/sqrt(hd)), Kh[b][h][n][32],
//   Vth[b][h][d][n] (transposed, for MFMA B-fragments).
// ---------------------------------------------------------------------------
__global__ __launch_bounds__(256) void qkv_gemm(
    const float* __restrict__ x, const float* __restrict__ W,
    const float* __restrict__ bias,
    _Float16* __restrict__ Qh, _Float16* __restrict__ Kh,
    _Float16* __restrict__ Vth)
{
    __shared__ float As[16][64];
    __shared__ float Bs[16][64];
    const int tid = threadIdx.x;
    const int m0 = blockIdx.y * 64;
    const int n0 = blockIdx.x * 64;
    const int tx = tid & 15, ty = tid >> 4;

    float acc[4][4];
#pragma unroll
    for (int i = 0; i < 4; i++)
#pragma unroll
        for (int j = 0; j < 4; j++) acc[i][j] = 0.0f;

    for (int kc = 0; kc < 256; kc += 16) {
        {
            int r  = tid >> 2;
            int c4 = tid & 3;
            float4 v = *(const float4*)&x[(m0 + r) * 256 + kc + c4 * 4];
            As[c4 * 4 + 0][r] = v.x;
            As[c4 * 4 + 1][r] = v.y;
            As[c4 * 4 + 2][r] = v.z;
            As[c4 * 4 + 3][r] = v.w;
        }
        {
            int kr = tid >> 4;
            int c4 = tid & 15;
            *(float4*)&Bs[kr][c4 * 4] =
                *(const float4*)&W[(kc + kr) * 768 + n0 + c4 * 4];
        }
        __syncthreads();
#pragma unroll
        for (int k = 0; k < 16; k++) {
            float a[4], bb[4];
            *(float4*)&a[0]  = *(float4*)&As[k][ty * 4];
            *(float4*)&bb[0] = *(float4*)&Bs[k][tx * 4];
#pragma unroll
            for (int i = 0; i < 4; i++)
#pragma unroll
                for (int j = 0; j < 4; j++) acc[i][j] += a[i] * bb[j];
        }
        __syncthreads();
    }

    const int col0  = n0 + tx * 4;
    const int which = col0 >> 8;
    const int h     = (col0 >> 5) & 7;
    const int hd0   = col0 & 31;
    const int b     = m0 >> 9;
    const int nr0   = (m0 & 511) + ty * 4;

    if (which < 2) {
        _Float16* base = (which == 0) ? Qh : Kh;
        const float sc = (which == 0) ? SCALE : 1.0f;
#pragma unroll
        for (int i = 0; i < 4; i++) {
            half4t hv;
#pragma unroll
            for (int j = 0; j < 4; j++)
                hv[j] = (_Float16)((acc[i][j] + bias[col0 + j]) * sc);
            *(half4t*)&base[(((size_t)(b * H_ + h)) * N_ + nr0 + i) * HD_ + hd0] = hv;
        }
    } else {
        // V transposed: Vth[b][h][d][n]
#pragma unroll
        for (int j = 0; j < 4; j++) {
            half4t hv;
            float bb = bias[col0 + j];
#pragma unroll
            for (int i = 0; i < 4; i++)
                hv[i] = (_Float16)(acc[i][j] + bb);
            *(half4t*)&Vth[(((size_t)(b * H_ + h)) * HD_ + hd0 + j) * N_ + nr0] = hv;
        }
    }
}

// ---------------------------------------------------------------------------
// Kernel 2: adj transpose + f16 convert: adjTh[b][v][u] = (f16) adj[b][u][v]
// ---------------------------------------------------------------------------
__global__ __launch_bounds__(256) void adj_transpose(
    const float* __restrict__ adj, _Float16* __restrict__ adjTh)
{
    __shared__ float t[64][65];
    const int bid = blockIdx.x;           // b*64 + vt*8 + ut
    const int b = bid >> 6, vt = (bid >> 3) & 7, ut = bid & 7;
    const int u0 = ut * 64, v0 = vt * 64;
    const int r  = threadIdx.x >> 4;      // 0..15
    const int c4 = (threadIdx.x & 15) * 4;

    const float* src = adj + ((size_t)b * N_ + u0) * N_ + v0;
#pragma unroll
    for (int it = 0; it < 4; it++) {
        int rr = r + it * 16;
        float4 v = *(const float4*)&src[rr * N_ + c4];
        t[rr][c4 + 0] = v.x; t[rr][c4 + 1] = v.y;
        t[rr][c4 + 2] = v.z; t[rr][c4 + 3] = v.w;
    }
    __syncthreads();
    _Float16* dst = adjTh + ((size_t)b * N_ + v0) * N_ + u0;
#pragma unroll
    for (int it = 0; it < 4; it++) {
        int rr = r + it * 16;
        half4t hv;
#pragma unroll
        for (int k = 0; k < 4; k++) hv[k] = (_Float16)t[c4 + k][rr];
        *(half4t*)&dst[rr * N_ + c4] = hv;
    }
}

// ---------------------------------------------------------------------------
// Kernel 3: per-edge modified focus log + transposed scatter-winner.
// selT[b][ev][eu] = max edge id (numpy last-write-wins).
// ---------------------------------------------------------------------------
__global__ __launch_bounds__(256) void edge_kernel(
    const float* __restrict__ edge_attr, const int* __restrict__ edge_index,
    const float* __restrict__ adj,
    const float* __restrict__ ds_W, const float* __restrict__ ds_b,
    const float* __restrict__ dw_W, const float* __restrict__ dw_b,
    const float* __restrict__ shifts, const float* __restrict__ widths,
    float* __restrict__ mlog, int* __restrict__ selT)
{
    __shared__ float ea[256 * 33];
    __shared__ float dsW[256], dwW[256];
    const int tid = threadIdx.x;
    const int b   = blockIdx.x >> 5;
    const int e0  = (blockIdx.x & 31) * 256;

    const float* eabase = edge_attr + ((size_t)b * E_ + e0) * EA_;
#pragma unroll
    for (int it = 0; it < 32; it++) {
        int i = tid + it * 256;
        ea[(i >> 5) * 33 + (i & 31)] = eabase[i];
    }
    dsW[tid] = ds_W[tid];
    dwW[tid] = dw_W[tid];
    __syncthreads();

    const int e  = e0 + tid;
    const int eu = edge_index[(size_t)b * 2 * E_ + e];
    const int ev = edge_index[(size_t)b * 2 * E_ + E_ + e];
    const float d = adj[((size_t)b * N_ + eu) * N_ + ev];

    float ds[8], dw[8];
#pragma unroll
    for (int h = 0; h < 8; h++) { ds[h] = ds_b[h]; dw[h] = dw_b[h]; }
#pragma unroll
    for (int k = 0; k < 32; k++) {
        float a = ea[tid * 33 + k];
#pragma unroll
        for (int h = 0; h < 8; h++) {
            ds[h] += a * dsW[k * 8 + h];
            dw[h] += a * dwW[k * 8 + h];
        }
    }
#pragma unroll
    for (int h = 0; h < 8; h++) {
        float ms = shifts[h] + ds[h];
        float mw = widths[h] + dw[h];
        float t  = d - ms;
        float ml = fmaxf(-(t * t) / (2.0f * mw * mw + 1e-6f), LOG1EM6);
        mlog[((size_t)(b * H_ + h)) * E_ + e] = ml;
    }
    atomicMax(&selT[((size_t)b * N_ + ev) * N_ + eu], e);
}

// ---------------------------------------------------------------------------
// helpers for the MFMA attn kernel
// ---------------------------------------------------------------------------
__device__ __forceinline__ unsigned pkf16(float x, float y)
{
    fp16x2 v = __builtin_amdgcn_cvt_pkrtz(x, y);   // D.lo = x, D.hi = y
    union { fp16x2 h; unsigned u; } c; c.h = v; return c.u;
}

// Build PV A-fragment for one k-half from p[0..7].
// gfx950 16-bit MFMA operand layout = two 4-elem k-blocks:
//   halves 0-3: k = (l>>5)*4 + j; halves 4-7: k = 8 + (l>>5)*4 + j.
// The S^T C/D layout delivers p[r] at exactly these positions -> lane-local.
__device__ __forceinline__ half8 pack_pfrag(const float* p)
{
    union { unsigned u[4]; half8 h; } r;
    r.u[0] = pkf16(p[0], p[1]);
    r.u[1] = pkf16(p[2], p[3]);
    r.u[2] = pkf16(p[4], p[5]);
    r.u[3] = pkf16(p[6], p[7]);
    return r.h;
}

// ---------------------------------------------------------------------------
// Kernel 4 v9: MFMA attention. One block per (b, h, 128-row tile); 4 waves,
// each wave owns 32 Q-rows. Swapped QK^T (A=K, B=Q) -> C holds S^T with
// col=lane&31=u (softmax lane-local; row=(r&3)+8*(r>>2)+4*hi per m74/m101).
// K/Q/V fragments all use the two-4-block k-map (consistent A/B map =>
// result correct under any true hw k-permutation). All cross-lane ops via
// __shfl_xor (no permlane semantics risk). Online softmax, defer-max THR=8.
// ---------------------------------------------------------------------------
__global__ __launch_bounds__(256, 1) void attn_kernel(
    const _Float16* __restrict__ Qh, const _Float16* __restrict__ Kh,
    const _Float16* __restrict__ Vth, const _Float16* __restrict__ adjTh,
    const float* __restrict__ mlog, const int* __restrict__ selT,
    const float* __restrict__ shifts, const float* __restrict__ widths,
    const float* __restrict__ slw_arr, float* __restrict__ out)
{
    extern __shared__ char lds[];         // [0,32K): K frags, [32K,64K): V frags

    const int tid  = threadIdx.x;
    const int bid  = blockIdx.x;          // b*32 + h*4 + rt
    const int b    = bid >> 5;
    const int h    = (bid >> 2) & 7;
    const int rt   = bid & 3;
    const int wv   = tid >> 6;
    const int lane = tid & 63;
    const int hi   = lane >> 5;
    const int u0w  = rt * 128 + wv * 32;

    const _Float16* Kg = Kh  + (size_t)(b * H_ + h) * N_ * HD_;
    const _Float16* Vg = Vth + (size_t)(b * H_ + h) * HD_ * N_;
    const _Float16* Qg = Qh  + (size_t)(b * H_ + h) * N_ * HD_;

    // ---- stage K as A-fragments (8B granules, two-4-block k-map).
    // chunk i8: row v = i8>>3, c8 = i8&7 covers halves c8*4..+4 (k-chunk).
    // kh = c8>>2, half-block hb = (c8>>1)&1, lane-group lhi = c8&1.
#pragma unroll
    for (int it = 0; it < 16; it++) {
        int i8 = tid + it * 256;          // 0..4095
        int v  = i8 >> 3;
        int c8 = i8 & 7;
        uint2 val = ((const uint2*)Kg)[i8];
        int off = ((v >> 5) * 2048) + ((c8 >> 2) * 1024) +
                  (((c8 & 1) * 32 + (v & 31)) * 16) + (((c8 >> 1) & 1) * 8);
        *(uint2*)(lds + off) = val;
    }
    // ---- stage V as B-fragments from Vth[d][n] (n = v index).
    // chunk i8: d = i8>>7, c = i8&127 covers n = c*4..+4.
    // vt = c>>3, kh = (c>>2)&1, hb = (c>>1)&1, lhi = c&1.
#pragma unroll
    for (int it = 0; it < 16; it++) {
        int i8 = tid + it * 256;          // 0..4095
        int d  = i8 >> 7;
        int c  = i8 & 127;
        uint2 val = ((const uint2*)Vg)[i8];
        int off = 32768 + ((c >> 3) * 2048) + (((c >> 2) & 1) * 1024) +
                  (((c & 1) * 32 + d) * 16) + (((c >> 1) & 1) * 8);
        *(uint2*)(lds + off) = val;
    }
    __syncthreads();

    // ---- Q B-fragments (2 k-halves), two-4-block map, pre-scaled by SCALE
    half8 qf0, qf1;
    {
        const _Float16* qrow = Qg + (size_t)(u0w + (lane & 31)) * HD_;
        union { uint2 w[2]; half8 h; } q0, q1;
        q0.w[0] = *(const uint2*)(qrow + hi * 4);          // k = hi*4..+4
        q0.w[1] = *(const uint2*)(qrow + 8 + hi * 4);      // k = 8+hi*4..+4
        q1.w[0] = *(const uint2*)(qrow + 16 + hi * 4);     // kh=1
        q1.w[1] = *(const uint2*)(qrow + 24 + hi * 4);
        qf0 = q0.h; qf1 = q1.h;
    }

    const float s_h   = shifts[h];
    const float w_h   = widths[h];
    const float inv2w = 1.0f / (2.0f * w_h * w_h + 1e-6f);
    const float slw   = slw_arr[h];
    const float* mlg  = mlog + (size_t)(b * H_ + h) * E_;
    const int ucol    = u0w + (lane & 31);

    f32x16 Oacc;
#pragma unroll
    for (int r = 0; r < 16; r++) Oacc[r] = 0.0f;
    float m = -1e30f, ssum = 0.0f;

    for (int vt = 0; vt < 16; vt++) {
        // ---- QK^T tile (S^T): 2 MFMA over k-halves
        half8 ka0 = *(const half8*)(lds + (vt * 2 + 0) * 1024 + lane * 16);
        half8 ka1 = *(const half8*)(lds + (vt * 2 + 1) * 1024 + lane * 16);
        f32x16 C;
#pragma unroll
        for (int r = 0; r < 16; r++) C[r] = 0.0f;
        C = __builtin_amdgcn_mfma_f32_32x32x16_f16(ka0, qf0, C, 0, 0, 0);
        C = __builtin_amdgcn_mfma_f32_32x32x16_f16(ka1, qf1, C, 0, 0, 0);

        // ---- adjust + tile max
        float p[16];
        float pmax = -1e30f;
        const int vbase = vt * 32 + 4 * hi;
#pragma unroll
        for (int r = 0; r < 16; r++) {
            int vg = vbase + (r & 3) + 8 * (r >> 2);
            int sidx = (b * N_ + vg) * N_ + ucol;
            int sv   = selT[sidx];
            float av = (float)adjTh[sidx];
            float ml = mlg[sv < 0 ? 0 : sv];
            float t  = av - s_h;
            float bl = fmaxf(-(t * t) * inv2w, LOG1EM6);
            float sc = C[r] + (sv >= 0 ? ml : bl);
            if (vg == ucol) sc += slw;
            p[r] = sc;
            pmax = fmaxf(pmax, sc);
        }
        pmax = fmaxf(pmax, __shfl_xor(pmax, 32, 64));   // merge lane-half pair

        // ---- defer-max online update (T13, THR=8)
        if (!__all(pmax - m <= 8.0f)) {
            float mnew = fmaxf(m, pmax);
            float scl  = __expf(m - mnew);              // per-u (u = lane&31)
#pragma unroll
            for (int r = 0; r < 16; r++) {
                int ur = (r & 3) + 8 * (r >> 2) + 4 * hi;
                Oacc[r] *= __shfl(scl, ur, 64);
            }
            ssum *= scl;
            m = mnew;
        }

        // ---- P = exp(s - m), accumulate denominator (partial per lane-half)
#pragma unroll
        for (int r = 0; r < 16; r++) {
            p[r] = __expf(p[r] - m);
            ssum += p[r];
        }

        // ---- pack P (lane-local) + PV MFMA
        half8 pa0 = pack_pfrag(&p[0]);
        half8 pa1 = pack_pfrag(&p[8]);
        half8 vb0 = *(const half8*)(lds + 32768 + (vt * 2 + 0) * 1024 + lane * 16);
        half8 vb1 = *(const half8*)(lds + 32768 + (vt * 2 + 1) * 1024 + lane * 16);
        Oacc = __builtin_amdgcn_mfma_f32_32x32x16_f16(pa0, vb0, Oacc, 0, 0, 0);
        Oacc = __builtin_amdgcn_mfma_f32_32x32x16_f16(pa1, vb1, Oacc, 0, 0, 0);
    }

    // ---- finalize: merge denominator across lane-half pair, normalize, store
    float stot = ssum + __shfl_xor(ssum, 32, 64);
    float rs = 1.0f / stot;
#pragma unroll
    for (int r = 0; r < 16; r++) {
        int ur = (r & 3) + 8 * (r >> 2) + 4 * hi;
        float o = Oacc[r] * __shfl(rs, ur, 64);
        int ug = u0w + ur;
        out[((size_t)(b * N_ + ug)) * D_ + h * HD_ + (lane & 31)] = o;
    }
}

// ---------------------------------------------------------------------------
extern "C" void kernel_launch(void* const* d_in, const int* in_sizes, int n_in,
                              void* d_out, int out_size, void* d_ws, size_t ws_size,
                              hipStream_t stream)
{
    const float* x          = (const float*)d_in[0];
    const float* adj        = (const float*)d_in[1];
    const int*   edge_index = (const int*)d_in[2];
    const float* edge_attr  = (const float*)d_in[3];
    const float* qkv_W      = (const float*)d_in[6];
    const float* qkv_b      = (const float*)d_in[7];
    const float* ds_W       = (const float*)d_in[12];
    const float* ds_b       = (const float*)d_in[13];
    const float* dw_W       = (const float*)d_in[14];
    const float* dw_b       = (const float*)d_in[15];
    const float* shifts     = (const float*)d_in[16];
    const float* widths     = (const float*)d_in[17];
    const float* slw        = (const float*)d_in[18];
    float* out = (float*)d_out;

    // workspace layout (20MB total, <= proven 22MB budget)
    _Float16* Qh   = (_Float16*)d_ws;                      // 2MB
    _Float16* Kh   = Qh + (size_t)B_ * H_ * N_ * HD_;      // 2MB
    _Float16* Vth  = Kh + (size_t)B_ * H_ * N_ * HD_;      // 2MB
    float*    mlog = (float*)(Vth + (size_t)B_ * H_ * N_ * HD_);   // 2MB
    int*      selT = (int*)(mlog + (size_t)B_ * H_ * E_);  // 8MB
    _Float16* adjTh = (_Float16*)(selT + (size_t)B_ * N_ * N_);    // 4MB

    hipMemsetAsync(selT, 0xFF, (size_t)B_ * N_ * N_ * sizeof(int), stream);

    qkv_gemm<<<dim3(12, 64), 256, 0, stream>>>(x, qkv_W, qkv_b, Qh, Kh, Vth);

    adj_transpose<<<dim3(512), 256, 0, stream>>>(adj, adjTh);

    edge_kernel<<<dim3(256), 256, 0, stream>>>(edge_attr, edge_index, adj,
                                               ds_W, ds_b, dw_W, dw_b,
                                               shifts, widths, mlog, selT);

    hipFuncSetAttribute((const void*)attn_kernel,
                        hipFuncAttributeMaxDynamicSharedMemorySize, 65536);
    attn_kernel<<<dim3(256), 256, 65536, stream>>>(Qh, Kh, Vth, adjTh,
                                                   mlog, selT,
                                                   shifts, widths, slw, out);
}